// Round 8
// baseline (232.618 us; speedup 1.0000x reference)
//
#include <hip/hip_runtime.h>

// ---------------------------------------------------------------------------
// RoPE attention: out = softmax(mask(RoPE(xWq^T) @ RoPE(xWk^T)^T / sqrt(d))) @ (xWv^T)
// B=4, T=2048, d=1024. fp32 in/out, bf16 MFMA internally.
// R19 -> R20: deep-pipeline GEMM engine for Q/K projection (A/B isolated).
// Evidence: qkv = 803 TF / MfmaUtil 33% / 0 bank conflicts / HBM 24% = the
// 2-barrier structure's ceiling; launch_bounds(256,4) didn't move occupancy
// (~28% both ways) so launch geometry is exhausted. New qk engine:
//  - 256x256 tile, 512 thr, 8 waves (2Mx4N), wave=128x64 (<8,4> frags):
//    43.7 FLOP/LDS-byte vs 21.9 in the <4,4> engine.
//  - BK=32, RING-4 LDS buffers (128 KB, 1 block/CU): iter kt stages tile
//    kt+3 into the slot last read at kt-1 (race-free by construction: reuse
//    separated by two barriers).
//  - counted s_waitcnt vmcnt(12) + raw s_barrier (NO __syncthreads -> no
//    vmcnt(0) drain = the m97 stall); sched_barrier(0) blocks ds_read hoist
//    past the barrier; setprio(1) around MFMA cluster.
//  - grid 32x8 = 256 blocks = 1 block/CU exact, no quantization.
// k-accumulation order identical -> Q/K bit-identical, absmax must stay
// 0.01171875 (changed absmax => race => revert). v/s/pv unchanged (R17: v=21).
// Predicted: qk 42 (R17) -> 23-31us; MfmaUtil 45-60%; total ~198-212.
// ---------------------------------------------------------------------------

typedef float f32x4 __attribute__((ext_vector_type(4)));
typedef __bf16 bf16x8 __attribute__((ext_vector_type(8)));

#define BM 128
#define BN 128
#define BK 64  // ushorts per LDS tile row; 128x64x2B = 16 KB per buffer

// packed-S geometry: stripe sb (0..15) holds [128][len], len=min(sb+2,16)*128
#define SP_BATCH 2473984  // 151 * 16384 ushorts per batch (4.72 MB)

__device__ __forceinline__ unsigned short f2bf(float f) {
  union { float f; unsigned int u; } c; c.f = f;
  unsigned int u = c.u;
  u += 0x7fffu + ((u >> 16) & 1u);  // round-nearest-even
  return (unsigned short)(u >> 16);
}
__device__ __forceinline__ float bf2f(unsigned short h) {
  union { unsigned int u; float f; } c; c.u = ((unsigned int)h) << 16;
  return c.f;
}

__device__ __forceinline__ void async16(const unsigned short* gp, unsigned short* lp) {
  __builtin_amdgcn_global_load_lds(
      (const __attribute__((address_space(1))) void*)gp,
      (__attribute__((address_space(3))) void*)lp, 16, 0, 0);
}

// ---------------------------------------------------------------------------
// All fp32->bf16 casts in one kernel; last block zeroes rowsums.
__global__ __launch_bounds__(256) void cvt_all(
    const float4* __restrict__ x, const float4* __restrict__ wq,
    const float4* __restrict__ wk, const float4* __restrict__ wv,
    ushort4* __restrict__ xb, ushort4* __restrict__ wb,
    float4* __restrict__ rowsums) {
  int b = blockIdx.x, t = threadIdx.x;
  if (b == 11264) {  // zero rowsums: 4*2048 fp32 = 2048 float4
#pragma unroll
    for (int i = 0; i < 8; ++i) rowsums[i * 256 + t] = float4{0.f, 0.f, 0.f, 0.f};
    return;
  }
  const float4* src;
  ushort4* dst;
  long i;
  if (b < 8192) { src = x; dst = xb; i = (long)b * 256 + t; }
  else if (b < 9216) { src = wq; dst = wb; i = (long)(b - 8192) * 256 + t; }
  else if (b < 10240) { src = wk; dst = wb + 262144; i = (long)(b - 9216) * 256 + t; }
  else { src = wv; dst = wb + 524288; i = (long)(b - 10240) * 256 + t; }
  float4 v = src[i];
  ushort4 o;
  o.x = f2bf(v.x); o.y = f2bf(v.y); o.z = f2bf(v.z); o.w = f2bf(v.w);
  dst[i] = o;
}

// ---------------------------------------------------------------------------
// NT-GEMM K-loop, BK=64, single-buffer global_load_lds staging (old engine;
// used by v/s/pv). See prior rounds for layout derivation.
template <int IM, int JN>
__device__ __forceinline__ void gemm_body(
    const unsigned short* __restrict__ A, const unsigned short* __restrict__ B,
    unsigned short* As, unsigned short* Bs,
    int lda, int ldb, int m0, int n0, int ktiles,
    int tid, int lane, int wave, f32x4 (&acc)[IM][JN]) {
  const int wm = (wave >> 1) * (IM * 16);
  const int wn = (wave & 1) * (JN * 16);
  const int fm = lane & 15;
  const int q = lane >> 4;
  const int srow = tid >> 3;                 // 0..31
  const int c = (tid & 7) ^ (srow & 7);      // staged 16-B chunk (p-invariant)
  const unsigned short* Ab = A + (long)(m0 + srow) * lda + c * 8;
  const unsigned short* Bb = B + (long)(n0 + srow) * ldb + c * 8;
  unsigned short* ldA = As + tid * 8;
  unsigned short* ldB = Bs + tid * 8;

  for (int kt = 0; kt < ktiles; ++kt) {
    const long k0 = (long)kt * BK;
    __syncthreads();  // prior frag reads done before LDS overwrite
#pragma unroll
    for (int p = 0; p < IM; ++p)
      async16(Ab + (long)(p * 32) * lda + k0, ldA + p * 2048);
#pragma unroll
    for (int p = 0; p < JN; ++p)
      async16(Bb + (long)(p * 32) * ldb + k0, ldB + p * 2048);
    __syncthreads();  // compiler drains vmcnt(0): tiles ready

#pragma unroll
    for (int s = 0; s < 2; ++s) {  // two k-steps of 32
      bf16x8 af[IM], bfr[JN];
#pragma unroll
      for (int i = 0; i < IM; ++i) {
        int row = wm + i * 16 + fm;
        af[i] = *(const bf16x8*)&As[row * 64 + ((((s << 2) | q) ^ (row & 7)) << 3)];
      }
#pragma unroll
      for (int j = 0; j < JN; ++j) {
        int row = wn + j * 16 + fm;
        bfr[j] = *(const bf16x8*)&Bs[row * 64 + ((((s << 2) | q) ^ (row & 7)) << 3)];
      }
#pragma unroll
      for (int i = 0; i < IM; ++i)
#pragma unroll
        for (int j = 0; j < JN; ++j)
          acc[i][j] = __builtin_amdgcn_mfma_f32_16x16x32_bf16(af[i], bfr[j], acc[i][j], 0, 0, 0);
    }
  }
}

// ---------------------------------------------------------------------------
// Q/K projection + RoPE, deep-pipeline 256x256 engine. A=xb[8192x1024],
// B=Wb[2048x1024]. Grid (32, 8), 512 threads.
// LDS chunk layout (per 16-KB half of a tile): chunk idx = row*4 + col16,
// row-major linear -> gload_lds dest = wave-uniform base + lane*16 with
// chunk = tid (+512 for upper half). Frag read af[i]: chunk (wm+i*16+fm)*4+q
// -> a wave reads a lane-permutation of 64 consecutive chunks = conflict-free
// (same class as the old engine's measured-0-conflict pattern).
__global__ __launch_bounds__(512, 2) void qk_rope_gemm256(
    const unsigned short* __restrict__ A, const unsigned short* __restrict__ B,
    unsigned short* __restrict__ Qr, unsigned short* __restrict__ Kr) {
  __shared__ __align__(16) unsigned short lds[4][2][8192];  // ring-4 x (A,B) x 16KB
  const int tid = threadIdx.x, lane = tid & 63, wave = tid >> 6;
  const int m0 = blockIdx.x * 256, n0 = blockIdx.y * 256;
  const int wm = (wave >> 2) * 128, wn = (wave & 3) * 64;
  const int q = lane >> 4, fm = lane & 15;
  const int r0 = tid >> 2, c16 = tid & 3;  // staging chunk tid: row, col16

  const unsigned short* Ab = A + (long)(m0 + r0) * 1024 + c16 * 8;
  const unsigned short* Bb = B + (long)(n0 + r0) * 1024 + c16 * 8;

  f32x4 acc[8][4];
#pragma unroll
  for (int i = 0; i < 8; ++i)
#pragma unroll
    for (int j = 0; j < 4; ++j) acc[i][j] = (f32x4)(0.f);

  // stage tile kt (A,B: 2 chunks each/thread) into ring slot kt&3
#define QSTAGE(kt)                                                     \
  {                                                                    \
    const int bi_ = (kt) & 3;                                          \
    const int ko_ = (kt) * 32;                                         \
    async16(Ab + ko_, &lds[bi_][0][tid * 8]);                          \
    async16(Ab + 131072 + ko_, &lds[bi_][0][tid * 8 + 4096]);          \
    async16(Bb + ko_, &lds[bi_][1][tid * 8]);                          \
    async16(Bb + 131072 + ko_, &lds[bi_][1][tid * 8 + 4096]);          \
  }

  // one K-tile of 32: 12 ds_read_b128 + 32 MFMA
#define QCOMPUTE(kt)                                                   \
  {                                                                    \
    const int bi_ = (kt) & 3;                                          \
    const unsigned short* As_ = lds[bi_][0];                           \
    const unsigned short* Bs_ = lds[bi_][1];                           \
    bf16x8 af[8], bfr[4];                                              \
    _Pragma("unroll") for (int i = 0; i < 8; ++i)                      \
        af[i] = *(const bf16x8*)&As_[((wm + i * 16 + fm) * 4 + q) * 8];\
    _Pragma("unroll") for (int j = 0; j < 4; ++j)                      \
        bfr[j] = *(const bf16x8*)&Bs_[((wn + j * 16 + fm) * 4 + q) * 8];\
    __builtin_amdgcn_s_setprio(1);                                     \
    _Pragma("unroll") for (int i = 0; i < 8; ++i)                      \
        _Pragma("unroll") for (int j = 0; j < 4; ++j)                  \
            acc[i][j] = __builtin_amdgcn_mfma_f32_16x16x32_bf16(       \
                af[i], bfr[j], acc[i][j], 0, 0, 0);                    \
    __builtin_amdgcn_s_setprio(0);                                     \
  }

  QSTAGE(0); QSTAGE(1); QSTAGE(2);  // prefetch depth 3 (12 loads in flight)
#pragma unroll 1
  for (int kt = 0; kt < 29; ++kt) {
    QSTAGE(kt + 3);  // into slot (kt-1)&3: reads done before kt-1's end barrier
    asm volatile("s_waitcnt vmcnt(12)" ::: "memory");  // own tile-kt loads done
    __builtin_amdgcn_s_barrier();                      // everyone's loads landed
    __builtin_amdgcn_sched_barrier(0);                 // no ds_read hoist above
    QCOMPUTE(kt);
    __builtin_amdgcn_s_barrier();                      // reads done before reuse
  }
  asm volatile("s_waitcnt vmcnt(8)" ::: "memory");
  __builtin_amdgcn_s_barrier();
  __builtin_amdgcn_sched_barrier(0);
  QCOMPUTE(29);
  __builtin_amdgcn_s_barrier();
  asm volatile("s_waitcnt vmcnt(4)" ::: "memory");
  __builtin_amdgcn_s_barrier();
  __builtin_amdgcn_sched_barrier(0);
  QCOMPUTE(30);
  __builtin_amdgcn_s_barrier();
  asm volatile("s_waitcnt vmcnt(0)" ::: "memory");
  __builtin_amdgcn_s_barrier();
  __builtin_amdgcn_sched_barrier(0);
  QCOMPUTE(31);

  // RoPE epilogue: pair (2c,2c+1) in adjacent lanes; chained angle addition.
  const float NEG = -13.287712379549449f / 1024.f;  // -log2(1e4)/1024
  unsigned short* dst = (n0 < 1024) ? Qr : Kr;
  const int t00 = (m0 + wm + q * 4) & 2047;
#pragma unroll
  for (int j = 0; j < 4; ++j) {
    int c = (n0 & 1023) + wn + j * 16 + fm;
    float th = exp2f((float)(c & ~1) * NEG);
    float sgn = (c & 1) ? 1.f : -1.f;
    float ang0 = (float)t00 * th;
    float cb = __cosf(ang0), sb = __sinf(ang0);
    float c1 = __cosf(th), s1 = __sinf(th);
    float cst = __cosf(16.f * th), sst = __sinf(16.f * th);
#pragma unroll
    for (int i = 0; i < 8; ++i) {
      int gmB = m0 + wm + i * 16 + q * 4;
      float cr = cb, sr = sb;
#pragma unroll
      for (int r = 0; r < 4; ++r) {
        float v = acc[i][j][r];
        float p = __shfl_xor(v, 1);
        dst[(long)(gmB + r) * 1024 + c] = f2bf(v * cr + sgn * p * sr);
        float crn = cr * c1 - sr * s1;
        sr = sr * c1 + cr * s1;
        cr = crn;
      }
      float cbn = cb * cst - sb * sst;
      sb = sb * cst + cb * sst;
      cb = cbn;
    }
  }
#undef QSTAGE
#undef QCOMPUTE
}

// ---------------------------------------------------------------------------
// V projection + transpose (old engine). A=xb[8192x1024], B=WbV[1024x1024].
// Grid (64, 8). R17 measured ~21us.
__global__ __launch_bounds__(256, 4) void v_gemm(
    const unsigned short* __restrict__ A, const unsigned short* __restrict__ B,
    unsigned short* __restrict__ Vt) {
  __shared__ __align__(16) unsigned short As[BM * BK];
  __shared__ __align__(16) unsigned short Bs[BN * BK];
  const int tid = threadIdx.x, lane = tid & 63, wave = tid >> 6;
  const int bm = blockIdx.x, bn = blockIdx.y;
  const int m0 = bm * BM, n0 = bn * BN;
  const int wm = (wave >> 1) * 64, wn = (wave & 1) * 64;
  const int q = lane >> 4, fm = lane & 15;

  f32x4 acc[4][4];
#pragma unroll
  for (int i = 0; i < 4; ++i)
#pragma unroll
    for (int j = 0; j < 4; ++j) acc[i][j] = (f32x4)(0.f);

  gemm_body<4, 4>(A, B, As, Bs, 1024, 1024, m0, n0, 16, tid, lane, wave, acc);

  // Transpose to Vt[b][c][t]; 4 consecutive t per lane -> 8-B stores.
#pragma unroll
  for (int j = 0; j < 4; ++j) {
    int c = n0 + wn + j * 16 + fm;
#pragma unroll
    for (int i = 0; i < 4; ++i) {
      int gmB = m0 + wm + i * 16 + q * 4;
      int b = gmB >> 11, t = gmB & 2047;
      ushort4 pk;
      pk.x = f2bf(acc[i][j][0]);
      pk.y = f2bf(acc[i][j][1]);
      pk.z = f2bf(acc[i][j][2]);
      pk.w = f2bf(acc[i][j][3]);
      *(ushort4*)&Vt[((long)b * 1024 + c) * 2048 + t] = pk;
    }
  }
}

// ---------------------------------------------------------------------------
// E = exp(mask(Qr@Kr^T)/32) per batch (z), bf16 PACKED triangular, + rowsums.
// 64x128 tiles (IM=2): grid 302/batch; fully-masked tiles zero-fill only.
__global__ __launch_bounds__(256, 4) void s_gemm(
    const unsigned short* __restrict__ Qr, const unsigned short* __restrict__ Kr,
    unsigned short* __restrict__ Sp, float* __restrict__ rowsums) {
  __shared__ __align__(16) unsigned short As[64 * BK];
  __shared__ __align__(16) unsigned short Bs[BN * BK];
  const int tid = threadIdx.x, lane = tid & 63, wave = tid >> 6;
  const int z = blockIdx.z;
  int idx = blockIdx.x, b = 31;
#pragma unroll 1
  for (; b > 0; --b) {  // per-b counts: min((b>>1)+2,16); total 302
    int cnt = ((b >> 1) + 2 > 16) ? 16 : (b >> 1) + 2;
    if (idx < cnt) break;
    idx -= cnt;
  }
  const int bn = idx;
  const int sb = b >> 1;
  const int len = ((sb + 2 > 16) ? 16 : sb + 2) * 128;
  unsigned short* S = Sp + (long)z * SP_BATCH + (long)(sb * (sb + 3) / 2) * 16384 +
                      (long)(b & 1) * 64 * len;

  if (128 * bn > 64 * b + 64) {
    // fully masked: zero the 64x128 region, no rowsum contribution
    ushort4 zz{0, 0, 0, 0};
#pragma unroll
    for (int u = 0; u < 8; ++u) {
      int e = tid * 8 + u;            // 2048 ushort4 covers 64x128
      int row = e >> 5, c4 = e & 31;  // 32 ushort4 per row
      *(ushort4*)&S[(long)row * len + bn * 128 + c4 * 4] = zz;
    }
    return;
  }

  const unsigned short* A = Qr + (long)z * 2048 * 1024;
  const unsigned short* B = Kr + (long)z * 2048 * 1024;
  float* rs = rowsums + (long)z * 2048;
  const int m0 = b * 64, n0 = bn * 128;
  const int wm = (wave >> 1) * 32, wn = (wave & 1) * 64;
  const int q = lane >> 4, fm = lane & 15;

  f32x4 acc[2][4];
#pragma unroll
  for (int i = 0; i < 2; ++i)
#pragma unroll
    for (int j = 0; j < 4; ++j) acc[i][j] = (f32x4)(0.f);

  gemm_body<2, 4>(A, B, As, Bs, 1024, 1024, m0, n0, 16, tid, lane, wave, acc);

  // rowsum scratch overlays Bs (frag reads complete after the final barrier)
  float* rsum = (float*)Bs;
  __syncthreads();
  if (tid < 64) rsum[tid] = 0.f;
  __syncthreads();

#pragma unroll
  for (int i = 0; i < 2; ++i) {
    int lr = wm + i * 16 + q * 4;  // stripe-half-local row 0..63
    int gmB = m0 + lr;             // global row
    float ps[4] = {0.f, 0.f, 0.f, 0.f};
#pragma unroll
    for (int j = 0; j < 4; ++j) {
      int gn = n0 + wn + j * 16 + fm;
#pragma unroll
      for (int r = 0; r < 4; ++r) {
        float e = (gn <= gmB + r + 1) ? __expf(acc[i][j][r] * 0.03125f) : 0.f;
        unsigned short h = f2bf(e);
        S[(long)(lr + r) * len + gn] = h;
        ps[r] += bf2f(h);  // sum the rounded value (matches stored E)
      }
    }
#pragma unroll
    for (int r = 0; r < 4; ++r) {
      float v = ps[r];
      v += __shfl_xor(v, 1);
      v += __shfl_xor(v, 2);
      v += __shfl_xor(v, 4);
      v += __shfl_xor(v, 8);
      if (fm == 0) atomicAdd(&rsum[lr + r], v);
    }
  }
  __syncthreads();
  if (tid < 64) atomicAdd(&rs[m0 + tid], rsum[tid]);
}

// ---------------------------------------------------------------------------
// out = (E @ Vt^T) / rowsum, K-loop truncated causally. Tile 64x128 (IM=2).
// SINGLE launch, grid dim3(32, 32): bn = x&7, z = x>>3, bm = 31-y.
__global__ __launch_bounds__(256, 4) void pv_gemm(
    const unsigned short* __restrict__ Sp, const unsigned short* __restrict__ Vt,
    const float* __restrict__ rowsums, float* __restrict__ out) {
  __shared__ __align__(16) unsigned short As[64 * BK];
  __shared__ __align__(16) unsigned short Bs[128 * BK];
  const int tid = threadIdx.x, lane = tid & 63, wave = tid >> 6;
  const int bn = blockIdx.x & 7;
  const int z = blockIdx.x >> 3;
  const int bm = 31 - blockIdx.y;  // 64-row granularity, longest-K first
  const int sb = bm >> 1;
  const int lda = ((sb + 2 > 16) ? 16 : sb + 2) * 128;
  const unsigned short* A = Sp + (long)z * SP_BATCH +
                            (long)(sb * (sb + 3) / 2) * 16384 +
                            (long)(bm & 1) * 64 * lda;
  const unsigned short* B = Vt + (long)z * 1024 * 2048;
  const float* rs = rowsums + (long)z * 2048;
  float* C = out + (long)z * 2048 * 1024;
  int ktiles = bm + 2;  // keys valid up to q+1, q <= m0+63; BK=64
  if (ktiles > 32) ktiles = 32;
  const int m0 = bm * 64, n0 = bn * 128;
  const int wm = (wave >> 1) * 32, wn = (wave & 1) * 64;
  const int q = lane >> 4, fm = lane & 15;

  f32x4 acc[2][4];
#pragma unroll
  for (int i = 0; i < 2; ++i)
#pragma unroll
    for (int j = 0; j < 4; ++j) acc[i][j] = (f32x4)(0.f);

  gemm_body<2, 4>(A, B, As, Bs, lda, 2048, 0, n0, ktiles, tid, lane, wave, acc);

#pragma unroll
  for (int i = 0; i < 2; ++i) {
    int gmB = m0 + wm + i * 16 + q * 4;
#pragma unroll
    for (int r = 0; r < 4; ++r) {
      float inv = 1.f / rs[gmB + r];
#pragma unroll
      for (int j = 0; j < 4; ++j) {
        int gn = n0 + wn + j * 16 + fm;
        C[(long)(gmB + r) * 1024 + gn] = acc[i][j][r] * inv;
      }
    }
  }
}

// ---------------------------------------------------------------------------
extern "C" void kernel_launch(void* const* d_in, const int* in_sizes, int n_in,
                              void* d_out, int out_size, void* d_ws, size_t ws_size,
                              hipStream_t stream) {
  const float* x = (const float*)d_in[0];
  const float* Wq = (const float*)d_in[1];
  const float* Wk = (const float*)d_in[2];
  const float* Wv = (const float*)d_in[3];
  float* out = (float*)d_out;

  // Layout: rowsums[32 KB] | Qr[16 MB] | Kr[16 MB] | Vt[16 MB] | xb[16 MB] |
  // Wb[6 MB]. Packed S (18.9 MB) overlays xb+Wb, dead after v_gemm.
  float* rowsums = (float*)d_ws;                      // [4][2048] fp32
  unsigned short* Qr = (unsigned short*)d_ws + 16384; // +32 KB
  unsigned short* Kr = Qr + (long)8192 * 1024;
  unsigned short* Vt = Kr + (long)8192 * 1024;        // [b][c][t]
  unsigned short* xb = Vt + (long)8192 * 1024;
  unsigned short* Wb = xb + (long)8192 * 1024;

  cvt_all<<<11265, 256, 0, stream>>>((const float4*)x, (const float4*)Wq,
                                     (const float4*)Wk, (const float4*)Wv,
                                     (ushort4*)xb, (ushort4*)Wb, (float4*)rowsums);

  // Q/K: deep-pipeline 256x256 engine, 256 blocks = 1/CU exact.
  qk_rope_gemm256<<<dim3(32, 8), 512, 0, stream>>>(xb, Wb, Qr, Kr);
  // V: old engine (proven ~21us), must finish before S overlays xb.
  v_gemm<<<dim3(64, 8), 256, 0, stream>>>(xb, Wb + (long)2048 * 1024, Vt);

  unsigned short* Sp = xb;  // packed S: 4 x 4.72 MB, spans xb + 2.9 MB of Wb
  s_gemm<<<dim3(302, 1, 4), 256, 0, stream>>>(Qr, Kr, Sp, rowsums);
  pv_gemm<<<dim3(32, 32), 256, 0, stream>>>(Sp, Vt, rowsums, out);
}

// Round 9
// 226.669 us; speedup vs baseline: 1.0262x; 1.0262x over previous
//
#include <hip/hip_runtime.h>

// ---------------------------------------------------------------------------
// RoPE attention: out = softmax(mask(RoPE(xWq^T) @ RoPE(xWk^T)^T / sqrt(d))) @ (xWv^T)
// B=4, T=2048, d=1024. fp32 in/out, bf16 MFMA internally.
// R20 -> R21: qk256 bank-conflict fix. R20 evidence: absmax bit-identical
// (ring-4 sync race-free) but SQ_LDS_BANK_CONFLICT = 3,145,728 = 786K
// ds_read_b128 x 4 extra cycles: read addr (row*4+q)*16B -> bank group
// (16(row&1)+4q)&31 -> within each 8-lane octet only 2 groups = 4-way.
// Fix (both-sides swizzle, rule 21): LDS pos (row,c) holds global chunk
// c ^ ((row>>1)&3). Stage: thread t sources chunk (t&3)^((t>>3)&3) (valid
// for both 128-row halves since 128>>1 = 64 == 0 mod 4). Read: chunk pos
// q ^ ((fm>>1)&3) (wm,wn,i*16,j*16 all vanish mod shifts). Octet check:
// group = (fm&1, q^((fm>>1)&3)) covers all 8 groups exactly once -> fully
// conflict-free. Sync structure untouched -> absmax must stay 0.01171875.
// Predicted: conflicts 3.1M -> <100K; qk256 53 -> ~43-46; MfmaUtil 23->~29.
// Decision rule: if qk256 >= old-engine share (~42 fast), revert to R19 qkv.
// ---------------------------------------------------------------------------

typedef float f32x4 __attribute__((ext_vector_type(4)));
typedef __bf16 bf16x8 __attribute__((ext_vector_type(8)));

#define BM 128
#define BN 128
#define BK 64  // ushorts per LDS tile row; 128x64x2B = 16 KB per buffer

// packed-S geometry: stripe sb (0..15) holds [128][len], len=min(sb+2,16)*128
#define SP_BATCH 2473984  // 151 * 16384 ushorts per batch (4.72 MB)

__device__ __forceinline__ unsigned short f2bf(float f) {
  union { float f; unsigned int u; } c; c.f = f;
  unsigned int u = c.u;
  u += 0x7fffu + ((u >> 16) & 1u);  // round-nearest-even
  return (unsigned short)(u >> 16);
}
__device__ __forceinline__ float bf2f(unsigned short h) {
  union { unsigned int u; float f; } c; c.u = ((unsigned int)h) << 16;
  return c.f;
}

__device__ __forceinline__ void async16(const unsigned short* gp, unsigned short* lp) {
  __builtin_amdgcn_global_load_lds(
      (const __attribute__((address_space(1))) void*)gp,
      (__attribute__((address_space(3))) void*)lp, 16, 0, 0);
}

// ---------------------------------------------------------------------------
// All fp32->bf16 casts in one kernel; last block zeroes rowsums.
__global__ __launch_bounds__(256) void cvt_all(
    const float4* __restrict__ x, const float4* __restrict__ wq,
    const float4* __restrict__ wk, const float4* __restrict__ wv,
    ushort4* __restrict__ xb, ushort4* __restrict__ wb,
    float4* __restrict__ rowsums) {
  int b = blockIdx.x, t = threadIdx.x;
  if (b == 11264) {  // zero rowsums: 4*2048 fp32 = 2048 float4
#pragma unroll
    for (int i = 0; i < 8; ++i) rowsums[i * 256 + t] = float4{0.f, 0.f, 0.f, 0.f};
    return;
  }
  const float4* src;
  ushort4* dst;
  long i;
  if (b < 8192) { src = x; dst = xb; i = (long)b * 256 + t; }
  else if (b < 9216) { src = wq; dst = wb; i = (long)(b - 8192) * 256 + t; }
  else if (b < 10240) { src = wk; dst = wb + 262144; i = (long)(b - 9216) * 256 + t; }
  else { src = wv; dst = wb + 524288; i = (long)(b - 10240) * 256 + t; }
  float4 v = src[i];
  ushort4 o;
  o.x = f2bf(v.x); o.y = f2bf(v.y); o.z = f2bf(v.z); o.w = f2bf(v.w);
  dst[i] = o;
}

// ---------------------------------------------------------------------------
// NT-GEMM K-loop, BK=64, single-buffer global_load_lds staging (old engine;
// used by v/s/pv). See prior rounds for layout derivation.
template <int IM, int JN>
__device__ __forceinline__ void gemm_body(
    const unsigned short* __restrict__ A, const unsigned short* __restrict__ B,
    unsigned short* As, unsigned short* Bs,
    int lda, int ldb, int m0, int n0, int ktiles,
    int tid, int lane, int wave, f32x4 (&acc)[IM][JN]) {
  const int wm = (wave >> 1) * (IM * 16);
  const int wn = (wave & 1) * (JN * 16);
  const int fm = lane & 15;
  const int q = lane >> 4;
  const int srow = tid >> 3;                 // 0..31
  const int c = (tid & 7) ^ (srow & 7);      // staged 16-B chunk (p-invariant)
  const unsigned short* Ab = A + (long)(m0 + srow) * lda + c * 8;
  const unsigned short* Bb = B + (long)(n0 + srow) * ldb + c * 8;
  unsigned short* ldA = As + tid * 8;
  unsigned short* ldB = Bs + tid * 8;

  for (int kt = 0; kt < ktiles; ++kt) {
    const long k0 = (long)kt * BK;
    __syncthreads();  // prior frag reads done before LDS overwrite
#pragma unroll
    for (int p = 0; p < IM; ++p)
      async16(Ab + (long)(p * 32) * lda + k0, ldA + p * 2048);
#pragma unroll
    for (int p = 0; p < JN; ++p)
      async16(Bb + (long)(p * 32) * ldb + k0, ldB + p * 2048);
    __syncthreads();  // compiler drains vmcnt(0): tiles ready

#pragma unroll
    for (int s = 0; s < 2; ++s) {  // two k-steps of 32
      bf16x8 af[IM], bfr[JN];
#pragma unroll
      for (int i = 0; i < IM; ++i) {
        int row = wm + i * 16 + fm;
        af[i] = *(const bf16x8*)&As[row * 64 + ((((s << 2) | q) ^ (row & 7)) << 3)];
      }
#pragma unroll
      for (int j = 0; j < JN; ++j) {
        int row = wn + j * 16 + fm;
        bfr[j] = *(const bf16x8*)&Bs[row * 64 + ((((s << 2) | q) ^ (row & 7)) << 3)];
      }
#pragma unroll
      for (int i = 0; i < IM; ++i)
#pragma unroll
        for (int j = 0; j < JN; ++j)
          acc[i][j] = __builtin_amdgcn_mfma_f32_16x16x32_bf16(af[i], bfr[j], acc[i][j], 0, 0, 0);
    }
  }
}

// ---------------------------------------------------------------------------
// Q/K projection + RoPE, deep-pipeline 256x256 engine. A=xb[8192x1024],
// B=Wb[2048x1024]. Grid (32, 8), 512 threads.
// LDS layout per 16-KB tile: 4x16B chunks/row; pos (row, c) holds global
// chunk c ^ ((row>>1)&3) (bank-conflict-free octets, see header).
__global__ __launch_bounds__(512, 2) void qk_rope_gemm256(
    const unsigned short* __restrict__ A, const unsigned short* __restrict__ B,
    unsigned short* __restrict__ Qr, unsigned short* __restrict__ Kr) {
  __shared__ __align__(16) unsigned short lds[4][2][8192];  // ring-4 x (A,B) x 16KB
  const int tid = threadIdx.x, lane = tid & 63, wave = tid >> 6;
  const int m0 = blockIdx.x * 256, n0 = blockIdx.y * 256;
  const int wm = (wave >> 2) * 128, wn = (wave & 3) * 64;
  const int q = lane >> 4, fm = lane & 15;
  const int r0 = tid >> 2;                          // staging row 0..127
  const int csw = (tid & 3) ^ ((tid >> 3) & 3);     // swizzled source chunk
  const int qx = q ^ ((fm >> 1) & 3);               // swizzled read chunk

  const unsigned short* Ab = A + (long)(m0 + r0) * 1024 + csw * 8;
  const unsigned short* Bb = B + (long)(n0 + r0) * 1024 + csw * 8;

  f32x4 acc[8][4];
#pragma unroll
  for (int i = 0; i < 8; ++i)
#pragma unroll
    for (int j = 0; j < 4; ++j) acc[i][j] = (f32x4)(0.f);

  // stage tile kt (A,B: 2 chunks each/thread) into ring slot kt&3
#define QSTAGE(kt)                                                     \
  {                                                                    \
    const int bi_ = (kt) & 3;                                          \
    const int ko_ = (kt) * 32;                                         \
    async16(Ab + ko_, &lds[bi_][0][tid * 8]);                          \
    async16(Ab + 131072 + ko_, &lds[bi_][0][tid * 8 + 4096]);          \
    async16(Bb + ko_, &lds[bi_][1][tid * 8]);                          \
    async16(Bb + 131072 + ko_, &lds[bi_][1][tid * 8 + 4096]);          \
  }

  // one K-tile of 32: 12 ds_read_b128 + 32 MFMA
#define QCOMPUTE(kt)                                                   \
  {                                                                    \
    const int bi_ = (kt) & 3;                                          \
    const unsigned short* As_ = lds[bi_][0];                           \
    const unsigned short* Bs_ = lds[bi_][1];                           \
    bf16x8 af[8], bfr[4];                                              \
    _Pragma("unroll") for (int i = 0; i < 8; ++i)                      \
        af[i] = *(const bf16x8*)&As_[((wm + i * 16 + fm) * 4 + qx) * 8];\
    _Pragma("unroll") for (int j = 0; j < 4; ++j)                      \
        bfr[j] = *(const bf16x8*)&Bs_[((wn + j * 16 + fm) * 4 + qx) * 8];\
    __builtin_amdgcn_s_setprio(1);                                     \
    _Pragma("unroll") for (int i = 0; i < 8; ++i)                      \
        _Pragma("unroll") for (int j = 0; j < 4; ++j)                  \
            acc[i][j] = __builtin_amdgcn_mfma_f32_16x16x32_bf16(       \
                af[i], bfr[j], acc[i][j], 0, 0, 0);                    \
    __builtin_amdgcn_s_setprio(0);                                     \
  }

  QSTAGE(0); QSTAGE(1); QSTAGE(2);  // prefetch depth 3 (12 loads in flight)
#pragma unroll 1
  for (int kt = 0; kt < 29; ++kt) {
    QSTAGE(kt + 3);  // into slot (kt-1)&3: reads done before kt-1's end barrier
    asm volatile("s_waitcnt vmcnt(12)" ::: "memory");  // own tile-kt loads done
    __builtin_amdgcn_s_barrier();                      // everyone's loads landed
    __builtin_amdgcn_sched_barrier(0);                 // no ds_read hoist above
    QCOMPUTE(kt);
    __builtin_amdgcn_s_barrier();                      // reads done before reuse
  }
  asm volatile("s_waitcnt vmcnt(8)" ::: "memory");
  __builtin_amdgcn_s_barrier();
  __builtin_amdgcn_sched_barrier(0);
  QCOMPUTE(29);
  __builtin_amdgcn_s_barrier();
  asm volatile("s_waitcnt vmcnt(4)" ::: "memory");
  __builtin_amdgcn_s_barrier();
  __builtin_amdgcn_sched_barrier(0);
  QCOMPUTE(30);
  __builtin_amdgcn_s_barrier();
  asm volatile("s_waitcnt vmcnt(0)" ::: "memory");
  __builtin_amdgcn_s_barrier();
  __builtin_amdgcn_sched_barrier(0);
  QCOMPUTE(31);

  // RoPE epilogue: pair (2c,2c+1) in adjacent lanes; chained angle addition.
  const float NEG = -13.287712379549449f / 1024.f;  // -log2(1e4)/1024
  unsigned short* dst = (n0 < 1024) ? Qr : Kr;
  const int t00 = (m0 + wm + q * 4) & 2047;
#pragma unroll
  for (int j = 0; j < 4; ++j) {
    int c = (n0 & 1023) + wn + j * 16 + fm;
    float th = exp2f((float)(c & ~1) * NEG);
    float sgn = (c & 1) ? 1.f : -1.f;
    float ang0 = (float)t00 * th;
    float cb = __cosf(ang0), sb = __sinf(ang0);
    float c1 = __cosf(th), s1 = __sinf(th);
    float cst = __cosf(16.f * th), sst = __sinf(16.f * th);
#pragma unroll
    for (int i = 0; i < 8; ++i) {
      int gmB = m0 + wm + i * 16 + q * 4;
      float cr = cb, sr = sb;
#pragma unroll
      for (int r = 0; r < 4; ++r) {
        float v = acc[i][j][r];
        float p = __shfl_xor(v, 1);
        dst[(long)(gmB + r) * 1024 + c] = f2bf(v * cr + sgn * p * sr);
        float crn = cr * c1 - sr * s1;
        sr = sr * c1 + cr * s1;
        cr = crn;
      }
      float cbn = cb * cst - sb * sst;
      sb = sb * cst + cb * sst;
      cb = cbn;
    }
  }
#undef QSTAGE
#undef QCOMPUTE
}

// ---------------------------------------------------------------------------
// V projection + transpose (old engine). A=xb[8192x1024], B=WbV[1024x1024].
// Grid (64, 8). R17 measured ~21us.
__global__ __launch_bounds__(256, 4) void v_gemm(
    const unsigned short* __restrict__ A, const unsigned short* __restrict__ B,
    unsigned short* __restrict__ Vt) {
  __shared__ __align__(16) unsigned short As[BM * BK];
  __shared__ __align__(16) unsigned short Bs[BN * BK];
  const int tid = threadIdx.x, lane = tid & 63, wave = tid >> 6;
  const int bm = blockIdx.x, bn = blockIdx.y;
  const int m0 = bm * BM, n0 = bn * BN;
  const int wm = (wave >> 1) * 64, wn = (wave & 1) * 64;
  const int q = lane >> 4, fm = lane & 15;

  f32x4 acc[4][4];
#pragma unroll
  for (int i = 0; i < 4; ++i)
#pragma unroll
    for (int j = 0; j < 4; ++j) acc[i][j] = (f32x4)(0.f);

  gemm_body<4, 4>(A, B, As, Bs, 1024, 1024, m0, n0, 16, tid, lane, wave, acc);

  // Transpose to Vt[b][c][t]; 4 consecutive t per lane -> 8-B stores.
#pragma unroll
  for (int j = 0; j < 4; ++j) {
    int c = n0 + wn + j * 16 + fm;
#pragma unroll
    for (int i = 0; i < 4; ++i) {
      int gmB = m0 + wm + i * 16 + q * 4;
      int b = gmB >> 11, t = gmB & 2047;
      ushort4 pk;
      pk.x = f2bf(acc[i][j][0]);
      pk.y = f2bf(acc[i][j][1]);
      pk.z = f2bf(acc[i][j][2]);
      pk.w = f2bf(acc[i][j][3]);
      *(ushort4*)&Vt[((long)b * 1024 + c) * 2048 + t] = pk;
    }
  }
}

// ---------------------------------------------------------------------------
// E = exp(mask(Qr@Kr^T)/32) per batch (z), bf16 PACKED triangular, + rowsums.
// 64x128 tiles (IM=2): grid 302/batch; fully-masked tiles zero-fill only.
__global__ __launch_bounds__(256, 4) void s_gemm(
    const unsigned short* __restrict__ Qr, const unsigned short* __restrict__ Kr,
    unsigned short* __restrict__ Sp, float* __restrict__ rowsums) {
  __shared__ __align__(16) unsigned short As[64 * BK];
  __shared__ __align__(16) unsigned short Bs[BN * BK];
  const int tid = threadIdx.x, lane = tid & 63, wave = tid >> 6;
  const int z = blockIdx.z;
  int idx = blockIdx.x, b = 31;
#pragma unroll 1
  for (; b > 0; --b) {  // per-b counts: min((b>>1)+2,16); total 302
    int cnt = ((b >> 1) + 2 > 16) ? 16 : (b >> 1) + 2;
    if (idx < cnt) break;
    idx -= cnt;
  }
  const int bn = idx;
  const int sb = b >> 1;
  const int len = ((sb + 2 > 16) ? 16 : sb + 2) * 128;
  unsigned short* S = Sp + (long)z * SP_BATCH + (long)(sb * (sb + 3) / 2) * 16384 +
                      (long)(b & 1) * 64 * len;

  if (128 * bn > 64 * b + 64) {
    // fully masked: zero the 64x128 region, no rowsum contribution
    ushort4 zz{0, 0, 0, 0};
#pragma unroll
    for (int u = 0; u < 8; ++u) {
      int e = tid * 8 + u;            // 2048 ushort4 covers 64x128
      int row = e >> 5, c4 = e & 31;  // 32 ushort4 per row
      *(ushort4*)&S[(long)row * len + bn * 128 + c4 * 4] = zz;
    }
    return;
  }

  const unsigned short* A = Qr + (long)z * 2048 * 1024;
  const unsigned short* B = Kr + (long)z * 2048 * 1024;
  float* rs = rowsums + (long)z * 2048;
  const int m0 = b * 64, n0 = bn * 128;
  const int wm = (wave >> 1) * 32, wn = (wave & 1) * 64;
  const int q = lane >> 4, fm = lane & 15;

  f32x4 acc[2][4];
#pragma unroll
  for (int i = 0; i < 2; ++i)
#pragma unroll
    for (int j = 0; j < 4; ++j) acc[i][j] = (f32x4)(0.f);

  gemm_body<2, 4>(A, B, As, Bs, 1024, 1024, m0, n0, 16, tid, lane, wave, acc);

  // rowsum scratch overlays Bs (frag reads complete after the final barrier)
  float* rsum = (float*)Bs;
  __syncthreads();
  if (tid < 64) rsum[tid] = 0.f;
  __syncthreads();

#pragma unroll
  for (int i = 0; i < 2; ++i) {
    int lr = wm + i * 16 + q * 4;  // stripe-half-local row 0..63
    int gmB = m0 + lr;             // global row
    float ps[4] = {0.f, 0.f, 0.f, 0.f};
#pragma unroll
    for (int j = 0; j < 4; ++j) {
      int gn = n0 + wn + j * 16 + fm;
#pragma unroll
      for (int r = 0; r < 4; ++r) {
        float e = (gn <= gmB + r + 1) ? __expf(acc[i][j][r] * 0.03125f) : 0.f;
        unsigned short h = f2bf(e);
        S[(long)(lr + r) * len + gn] = h;
        ps[r] += bf2f(h);  // sum the rounded value (matches stored E)
      }
    }
#pragma unroll
    for (int r = 0; r < 4; ++r) {
      float v = ps[r];
      v += __shfl_xor(v, 1);
      v += __shfl_xor(v, 2);
      v += __shfl_xor(v, 4);
      v += __shfl_xor(v, 8);
      if (fm == 0) atomicAdd(&rsum[lr + r], v);
    }
  }
  __syncthreads();
  if (tid < 64) atomicAdd(&rs[m0 + tid], rsum[tid]);
}

// ---------------------------------------------------------------------------
// out = (E @ Vt^T) / rowsum, K-loop truncated causally. Tile 64x128 (IM=2).
// SINGLE launch, grid dim3(32, 32): bn = x&7, z = x>>3, bm = 31-y.
__global__ __launch_bounds__(256, 4) void pv_gemm(
    const unsigned short* __restrict__ Sp, const unsigned short* __restrict__ Vt,
    const float* __restrict__ rowsums, float* __restrict__ out) {
  __shared__ __align__(16) unsigned short As[64 * BK];
  __shared__ __align__(16) unsigned short Bs[128 * BK];
  const int tid = threadIdx.x, lane = tid & 63, wave = tid >> 6;
  const int bn = blockIdx.x & 7;
  const int z = blockIdx.x >> 3;
  const int bm = 31 - blockIdx.y;  // 64-row granularity, longest-K first
  const int sb = bm >> 1;
  const int lda = ((sb + 2 > 16) ? 16 : sb + 2) * 128;
  const unsigned short* A = Sp + (long)z * SP_BATCH +
                            (long)(sb * (sb + 3) / 2) * 16384 +
                            (long)(bm & 1) * 64 * lda;
  const unsigned short* B = Vt + (long)z * 1024 * 2048;
  const float* rs = rowsums + (long)z * 2048;
  float* C = out + (long)z * 2048 * 1024;
  int ktiles = bm + 2;  // keys valid up to q+1, q <= m0+63; BK=64
  if (ktiles > 32) ktiles = 32;
  const int m0 = bm * 64, n0 = bn * 128;
  const int wm = (wave >> 1) * 32, wn = (wave & 1) * 64;
  const int q = lane >> 4, fm = lane & 15;

  f32x4 acc[2][4];
#pragma unroll
  for (int i = 0; i < 2; ++i)
#pragma unroll
    for (int j = 0; j < 4; ++j) acc[i][j] = (f32x4)(0.f);

  gemm_body<2, 4>(A, B, As, Bs, lda, 2048, 0, n0, ktiles, tid, lane, wave, acc);

#pragma unroll
  for (int i = 0; i < 2; ++i) {
    int gmB = m0 + wm + i * 16 + q * 4;
#pragma unroll
    for (int r = 0; r < 4; ++r) {
      float inv = 1.f / rs[gmB + r];
#pragma unroll
      for (int j = 0; j < 4; ++j) {
        int gn = n0 + wn + j * 16 + fm;
        C[(long)(gmB + r) * 1024 + gn] = acc[i][j][r] * inv;
      }
    }
  }
}

// ---------------------------------------------------------------------------
extern "C" void kernel_launch(void* const* d_in, const int* in_sizes, int n_in,
                              void* d_out, int out_size, void* d_ws, size_t ws_size,
                              hipStream_t stream) {
  const float* x = (const float*)d_in[0];
  const float* Wq = (const float*)d_in[1];
  const float* Wk = (const float*)d_in[2];
  const float* Wv = (const float*)d_in[3];
  float* out = (float*)d_out;

  // Layout: rowsums[32 KB] | Qr[16 MB] | Kr[16 MB] | Vt[16 MB] | xb[16 MB] |
  // Wb[6 MB]. Packed S (18.9 MB) overlays xb+Wb, dead after v_gemm.
  float* rowsums = (float*)d_ws;                      // [4][2048] fp32
  unsigned short* Qr = (unsigned short*)d_ws + 16384; // +32 KB
  unsigned short* Kr = Qr + (long)8192 * 1024;
  unsigned short* Vt = Kr + (long)8192 * 1024;        // [b][c][t]
  unsigned short* xb = Vt + (long)8192 * 1024;
  unsigned short* Wb = xb + (long)8192 * 1024;

  cvt_all<<<11265, 256, 0, stream>>>((const float4*)x, (const float4*)Wq,
                                     (const float4*)Wk, (const float4*)Wv,
                                     (ushort4*)xb, (ushort4*)Wb, (float4*)rowsums);

  // Q/K: deep-pipeline 256x256 engine, 256 blocks = 1/CU exact.
  qk_rope_gemm256<<<dim3(32, 8), 512, 0, stream>>>(xb, Wb, Qr, Kr);
  // V: old engine (proven ~21us), must finish before S overlays xb.
  v_gemm<<<dim3(64, 8), 256, 0, stream>>>(xb, Wb + (long)2048 * 1024, Vt);

  unsigned short* Sp = xb;  // packed S: 4 x 4.72 MB, spans xb + 2.9 MB of Wb
  s_gemm<<<dim3(302, 1, 4), 256, 0, stream>>>(Qr, Kr, Sp, rowsums);
  pv_gemm<<<dim3(32, 32), 256, 0, stream>>>(Sp, Vt, rowsums, out);
}